// Round 1
// baseline (607.623 us; speedup 1.0000x reference)
//
#include <hip/hip_runtime.h>

// GCN layer: out = sum_r segment_sum(vals_r * inp[src_r], dst_r) @ W_r
// Restructured: h_r = inp @ W_r (dense GEMM), then out[dst] += val * h_r[src].
// N=50000, R=8, E=100000, IN=OUT=128, all f32.

constexpr int IN  = 128;
constexpr int OUT = 128;
constexpr int KH  = 64;          // k-half staged in LDS (Ws = 32 KB)
constexpr int GEMM_TILE = 32;    // rows per inner tile (As = 8 KB)
constexpr int GEMM_ROWS = 128;   // rows per block
constexpr int EDGES_PER_BLOCK = 8;  // 256 threads / 32 lanes per edge

// ---------------- GEMM: h = inp @ W[r]  (per-relation, or fused via grid.y) ---
__global__ __launch_bounds__(256) void gemm_kernel(
    const float* __restrict__ inp, const float* __restrict__ weights,
    float* __restrict__ h, int rel_base, long long h_stride,
    int node_lo, int node_hi)
{
    const int r = rel_base + blockIdx.y;
    const float* W = weights + (size_t)r * IN * OUT;
    float* hout = h + (size_t)blockIdx.y * h_stride;

    __shared__ float Ws[KH][OUT];        // 32 KB
    __shared__ float As[GEMM_TILE][KH];  // 8 KB

    const int tid = threadIdx.x;
    const int cg  = tid & 31;      // col group: cols cg*4 .. cg*4+3
    const int rg  = tid >> 5;      // row group: rows rg*4 .. rg*4+3
    const int c0  = cg * 4;

    const int row0 = node_lo + blockIdx.x * GEMM_ROWS;

    for (int t = 0; t < GEMM_ROWS / GEMM_TILE; ++t) {
        const int rowbase = row0 + t * GEMM_TILE;
        float4 acc[4];
        #pragma unroll
        for (int i = 0; i < 4; ++i) acc[i] = make_float4(0.f, 0.f, 0.f, 0.f);

        for (int kh = 0; kh < IN / KH; ++kh) {
            __syncthreads();   // protect LDS from previous iteration's readers
            // stage W k-half: KH*OUT floats = 2048 float4, 8 per thread
            {
                const float4* Wv = (const float4*)(W + (size_t)kh * KH * OUT);
                float4* Wsv = (float4*)&Ws[0][0];
                for (int i = tid; i < KH * OUT / 4; i += 256) Wsv[i] = Wv[i];
            }
            // stage A tile: 32 rows x KH cols = 512 float4, 2 per thread
            {
                float4* Asv = (float4*)&As[0][0];
                for (int i = tid; i < GEMM_TILE * KH / 4; i += 256) {
                    const int fi = i * 4;
                    const int rr = rowbase + fi / KH;
                    const int cc = (fi & (KH - 1)) + kh * KH;
                    float4 v = make_float4(0.f, 0.f, 0.f, 0.f);
                    if (rr < node_hi)
                        v = *(const float4*)(inp + (size_t)rr * IN + cc);
                    Asv[i] = v;
                }
            }
            __syncthreads();

            #pragma unroll 4
            for (int k4 = 0; k4 < KH / 4; ++k4) {
                float4 a[4], w[4];
                #pragma unroll
                for (int i = 0; i < 4; ++i)
                    a[i] = *(const float4*)&As[rg * 4 + i][k4 * 4];
                #pragma unroll
                for (int kk = 0; kk < 4; ++kk)
                    w[kk] = *(const float4*)&Ws[k4 * 4 + kk][c0];
                #pragma unroll
                for (int i = 0; i < 4; ++i) {
                    acc[i].x += a[i].x*w[0].x + a[i].y*w[1].x + a[i].z*w[2].x + a[i].w*w[3].x;
                    acc[i].y += a[i].x*w[0].y + a[i].y*w[1].y + a[i].z*w[2].y + a[i].w*w[3].y;
                    acc[i].z += a[i].x*w[0].z + a[i].y*w[1].z + a[i].z*w[2].z + a[i].w*w[3].z;
                    acc[i].w += a[i].x*w[0].w + a[i].y*w[1].w + a[i].z*w[2].w + a[i].w*w[3].w;
                }
            }
        }

        #pragma unroll
        for (int i = 0; i < 4; ++i) {
            const int row = rowbase + rg * 4 + i;
            if (row < node_hi)
                *(float4*)(hout + (size_t)(row - node_lo) * OUT + c0) = acc[i];
        }
    }
}

// ---------------- Scatter: out[dst] += val * h[src] -------------------------
__global__ __launch_bounds__(256) void scatter_kernel(
    const float* __restrict__ h, const int* __restrict__ src,
    const int* __restrict__ dst, const float* __restrict__ vals,
    float* __restrict__ out, int rel_base, long long h_stride,
    int node_lo, int node_hi, int n_edges)
{
    const int r = rel_base + blockIdx.y;
    const float* hrel = h + (size_t)blockIdx.y * h_stride;

    const int e = blockIdx.x * EDGES_PER_BLOCK + (threadIdx.x >> 5);
    if (e >= n_edges) return;
    const int lane = threadIdx.x & 31;

    const size_t eidx = (size_t)r * n_edges + e;
    const int s = src[eidx];
    if (s < node_lo || s >= node_hi) return;
    const int d = dst[eidx];
    const float v = vals[eidx];

    const float* hrow = hrel + (size_t)(s - node_lo) * OUT;
    float* orow = out + (size_t)d * OUT;

    // lane handles cols lane, lane+32, lane+64, lane+96: loads fully coalesced,
    // each atomic instruction covers a contiguous 128B span.
    #pragma unroll
    for (int kk = 0; kk < 4; ++kk) {
        const int j = lane + kk * 32;
        const float m = v * hrow[j];
        __hip_atomic_fetch_add(orow + j, m, __ATOMIC_RELAXED,
                               __HIP_MEMORY_SCOPE_AGENT);
    }
}

extern "C" void kernel_launch(void* const* d_in, const int* in_sizes, int n_in,
                              void* d_out, int out_size, void* d_ws, size_t ws_size,
                              hipStream_t stream) {
    const float* inp     = (const float*)d_in[0];
    const int*   src     = (const int*)  d_in[1];
    const int*   dst     = (const int*)  d_in[2];
    const float* vals    = (const float*)d_in[3];
    const float* weights = (const float*)d_in[4];
    float* out = (float*)d_out;

    const int n_nodes = in_sizes[0] / IN;            // 50000
    const int n_rel   = in_sizes[4] / (IN * OUT);    // 8
    const int n_edges = in_sizes[1] / n_rel;         // 100000

    hipMemsetAsync(out, 0, (size_t)n_nodes * OUT * sizeof(float), stream);

    float* h = (float*)d_ws;
    const size_t per_rel = (size_t)n_nodes * OUT * sizeof(float);   // 25.6 MB
    const int sgx = (n_edges + EDGES_PER_BLOCK - 1) / EDGES_PER_BLOCK;

    if (ws_size >= per_rel * (size_t)n_rel) {
        // Fused path: all 8 h_r live in ws; 1 GEMM + 1 scatter dispatch.
        const long long hstride = (long long)n_nodes * OUT;
        dim3 ggrid((n_nodes + GEMM_ROWS - 1) / GEMM_ROWS, n_rel);
        gemm_kernel<<<ggrid, 256, 0, stream>>>(inp, weights, h, 0, hstride,
                                               0, n_nodes);
        dim3 sgrid(sgx, n_rel);
        scatter_kernel<<<sgrid, 256, 0, stream>>>(h, src, dst, vals, out,
                                                  0, hstride, 0, n_nodes, n_edges);
    } else {
        // Chunked fallback: h covers node rows [lo,hi) for one relation.
        int chunk = (int)(ws_size / (OUT * sizeof(float)));
        if (chunk < 1) chunk = 1;
        if (chunk > n_nodes) chunk = n_nodes;
        for (int r = 0; r < n_rel; ++r) {
            for (int lo = 0; lo < n_nodes; lo += chunk) {
                const int hi = (lo + chunk < n_nodes) ? (lo + chunk) : n_nodes;
                dim3 ggrid((hi - lo + GEMM_ROWS - 1) / GEMM_ROWS, 1);
                gemm_kernel<<<ggrid, 256, 0, stream>>>(inp, weights, h, r, 0,
                                                       lo, hi);
                dim3 sgrid(sgx, 1);
                scatter_kernel<<<sgrid, 256, 0, stream>>>(h, src, dst, vals, out,
                                                          r, 0, lo, hi, n_edges);
            }
        }
    }
}